// Round 7
// baseline (62.357 us; speedup 1.0000x reference)
//
#include <hip/hip_runtime.h>

// Per-channel histogram: in [LENGTH=1e6, C=64] int32 values in [0,256),
// out [64, 256] int32 counts. Memory-bound: 256 MB read.
//
// R7: single-lever A/B vs R6 - BLOCKS 256 -> 512 (2 blocks/CU, 32 waves/CU).
// Theory: read-only BW is outstanding-load-limited per CU at 16 waves
// (~4.8 TB/s observed vs 6.3 achievable); doubling resident waves doubles
// issue continuity / tracking capacity. NO launch_bounds VGPR cap (R3/R5's
// confound): body is lean enough to sit <=64 VGPR naturally; if not, we
// degrade to 1 block/CU == R6 == neutral, which is itself informative.
// Everything else identical to R6: contiguous per-block segments, depth-2
// load batch, 64 KB LDS hist, packed 64-bit rotated flush.

#define NCH   64
#define NBINS 256
#define HIST_SIZE (NCH * NBINS)   // 16384 ints = 64 KB LDS
#define NQWORDS   (HIST_SIZE / 2) // 8192 packed pairs
#define THREADS 1024
#define BLOCKS  512               // 2 blocks/CU

__global__ __launch_bounds__(THREADS) void hist_kernel(
    const int* __restrict__ in, unsigned long long* __restrict__ out,
    long long n4)
{
    __shared__ int hist[HIST_SIZE];
    const int tid = threadIdx.x;

    #pragma unroll
    for (int k = 0; k < HIST_SIZE / THREADS; ++k)
        hist[tid + k * THREADS] = 0;
    __syncthreads();

    const int4* __restrict__ in4 = (const int4*)in;

    // Contiguous per-block segment [seg0, seg_end).
    const long long per_block = (n4 + BLOCKS - 1) / BLOCKS;   // 31250
    const long long seg0 = (long long)blockIdx.x * per_block;
    const long long seg_end = (seg0 + per_block < n4) ? (seg0 + per_block) : n4;
    const int seg_len = (int)(seg_end - seg0);                // <= 31250

    // int4 m covers flat ints [4m,4m+4) -> channels (m&15)*4..+3.
    // All loop steps are multiples of 1024 -> (m&15) per-thread constant.
    const int c0 = (int)(((seg0 + tid) & 15) << 2);
    int* __restrict__ h = &hist[c0 * NBINS];

    const int4* __restrict__ base = in4 + seg0;

    // Depth-2 main loop: block reads 2x16KB contiguous per iteration.
    const int full2 = seg_len / (2 * THREADS);                // 15
    for (int k = 0; k < full2; ++k) {
        const int j = k * 2 * THREADS + tid;
        int4 a = base[j];
        int4 b = base[j + THREADS];
        atomicAdd(&h[0 * NBINS + a.x], 1); atomicAdd(&h[1 * NBINS + a.y], 1);
        atomicAdd(&h[2 * NBINS + a.z], 1); atomicAdd(&h[3 * NBINS + a.w], 1);
        atomicAdd(&h[0 * NBINS + b.x], 1); atomicAdd(&h[1 * NBINS + b.y], 1);
        atomicAdd(&h[2 * NBINS + b.z], 1); atomicAdd(&h[3 * NBINS + b.w], 1);
    }
    // Tail: up to 2*THREADS-1 int4 remain (steps stay multiples of THREADS).
    int j = full2 * 2 * THREADS + tid;
    if (j < seg_len) {
        int4 a = base[j];
        atomicAdd(&h[0 * NBINS + a.x], 1); atomicAdd(&h[1 * NBINS + a.y], 1);
        atomicAdd(&h[2 * NBINS + a.z], 1); atomicAdd(&h[3 * NBINS + a.w], 1);
    }
    j += THREADS;
    if (j < seg_len) {
        int4 a = base[j];
        atomicAdd(&h[0 * NBINS + a.x], 1); atomicAdd(&h[1 * NBINS + a.y], 1);
        atomicAdd(&h[2 * NBINS + a.z], 1); atomicAdd(&h[3 * NBINS + a.w], 1);
    }
    __syncthreads();

    // Flush block-private histogram as packed 64-bit adds (two bins/atomic).
    // Per-bin totals << 2^32 -> no carry across halves. Rotate start offset
    // per block to spread L2 line contention. (R1 vs R2: flush atomic count
    // is not a limiter, so 512-block flush doubling is ~free.)
    const unsigned long long* __restrict__ h64 = (const unsigned long long*)hist;
    #pragma unroll
    for (int kk = 0; kk < NQWORDS / THREADS; ++kk) {
        const int jj = (tid + kk * THREADS + blockIdx.x * 32) & (NQWORDS - 1);
        const unsigned long long v = h64[jj];
        if (v) atomicAdd(&out[jj], v);
    }
}

extern "C" void kernel_launch(void* const* d_in, const int* in_sizes, int n_in,
                              void* d_out, int out_size, void* d_ws, size_t ws_size,
                              hipStream_t stream) {
    const int* in = (const int*)d_in[0];
    unsigned long long* out = (unsigned long long*)d_out;
    const long long n = (long long)in_sizes[0];   // 64,000,000 (divisible by 4)
    const long long n4 = n / 4;

    // Replays accumulate via atomics -> must zero the output every launch.
    hipMemsetAsync(d_out, 0, (size_t)out_size * sizeof(int), stream);

    hist_kernel<<<BLOCKS, THREADS, 0, stream>>>(in, out, n4);
}